// Round 5
// baseline (9429.396 us; speedup 1.0000x reference)
//
#include <hip/hip_runtime.h>

// MyRnn persistent v2: whole 80-step 2-layer RNN in ONE cooperative kernel.
// KC=128 (32 KB LDS -> cooperative occupancy check passes at 512 blocks).
// Fallback: if hipLaunchCooperativeKernel errors, run the proven 81-launch path.

typedef _Float16 h8v __attribute__((ext_vector_type(8)));
typedef float    f4v __attribute__((ext_vector_type(4)));
typedef short    s8v __attribute__((ext_vector_type(8)));

#define UNITS 1024
#define SEQ   80
#define EMBD  100
#define EPAD  128
#define KC    128
#define NBLK  512

__device__ __forceinline__ float tanh_fast(float x) {
    x = fminf(15.f, fmaxf(-15.f, x));   // also scrubs NaN
    float e = __expf(2.f * x);
    return (e - 1.f) / (e + 1.f);
}

__device__ __forceinline__ void gl_lds16(const _Float16* g, _Float16* l) {
    __builtin_amdgcn_global_load_lds(
        (const __attribute__((address_space(1))) void*)g,
        (__attribute__((address_space(3))) void*)l, 16, 0, 0);
}

// ---------------- prep kernels ----------------

__global__ void embp_kernel(const float* __restrict__ emb, _Float16* __restrict__ embp) {
    int r = blockIdx.x, k = threadIdx.x;
    embp[r * EPAD + k] = (k < EMBD) ? (_Float16)emb[r * EMBD + k] : (_Float16)0.f;
}

__global__ void tpad_kernel(const float* __restrict__ w, _Float16* __restrict__ wt,
                            int K, int Kpad, int N) {
    __shared__ float t[32][33];
    int k0 = blockIdx.x * 32, n0 = blockIdx.y * 32;
    int tx = threadIdx.x, ty = threadIdx.y;
    for (int i = ty; i < 32; i += 8) {
        int k = k0 + i;
        t[i][tx] = (k < K) ? w[(size_t)k * N + n0 + tx] : 0.f;
    }
    __syncthreads();
    for (int i = ty; i < 32; i += 8)
        wt[(size_t)(n0 + i) * Kpad + k0 + tx] = (_Float16)t[tx][i];
}

__global__ void zero_kernel(s8v* __restrict__ p) {
    p[blockIdx.x * 256 + threadIdx.x] = (s8v)0;
}

// ---------------- shared GEMM tile code (KC=128, proven in R3) ----------------

struct TileGeom {
    int rq[4], ldsoff[4], koff[4];   // staging geometry per wave-instr
    int lane, w, wm, wn, quad, l16;
};

__device__ __forceinline__ TileGeom make_geom(int tid) {
    TileGeom G;
    G.lane = tid & 63; G.w = tid >> 6;
    G.wm = G.w >> 1;   G.wn = G.w & 1;
    G.quad = G.lane >> 4; G.l16 = G.lane & 15;
    #pragma unroll
    for (int q = 0; q < 4; ++q) {
        int g = G.w * 4 + q;
        int r = g * 4 + (G.lane >> 4);
        G.rq[q] = r;
        G.ldsoff[q] = g * 512;
        G.koff[q] = 8 * ((G.lane & 15) ^ (r & 7));
    }
    return G;
}

// stage one KC-chunk of A (rows row0..row0+63 of arow-provider) and B, then MFMA
template <bool GATHER>
__device__ __forceinline__ void gemm_chunk(
    const TileGeom& G, _Float16* As, _Float16* Bs,
    const _Float16* A, int lda, const int* xi,
    const _Float16* Bt, int ldb, int row0, int col0, int k0, f4v acc[2][2]) {
    #pragma unroll
    for (int q = 0; q < 4; ++q) {
        int r = G.rq[q];
        const _Float16* ap;
        if (GATHER)
            ap = A + (size_t)xi[(size_t)(row0 + r) * SEQ] * EPAD + k0 + G.koff[q];
        else
            ap = A + (size_t)(row0 + r) * lda + k0 + G.koff[q];
        const _Float16* bp = Bt + (size_t)(col0 + r) * ldb + k0 + G.koff[q];
        gl_lds16(ap, As + G.ldsoff[q]);
        gl_lds16(bp, Bs + G.ldsoff[q]);
    }
    __syncthreads();
    #pragma unroll
    for (int kk = 0; kk < 4; ++kk) {
        int us = 8 * ((kk * 4 + G.quad) ^ (G.l16 & 7));
        h8v af[2], bf[2];
        #pragma unroll
        for (int i = 0; i < 2; ++i)
            af[i] = *(const h8v*)(As + (G.wm * 32 + i * 16 + G.l16) * KC + us);
        #pragma unroll
        for (int j = 0; j < 2; ++j)
            bf[j] = *(const h8v*)(Bs + (G.wn * 32 + j * 16 + G.l16) * KC + us);
        #pragma unroll
        for (int i = 0; i < 2; ++i)
            #pragma unroll
            for (int j = 0; j < 2; ++j)
                acc[i][j] = __builtin_amdgcn_mfma_f32_16x16x32_f16(
                    af[i], bf[j], acc[i][j], 0, 0, 0);
    }
    __syncthreads();
}

__device__ __forceinline__ void epilogue(
    const TileGeom& G, f4v acc[2][2], const float* bias, _Float16* outp,
    int row0, int col0) {
    #pragma unroll
    for (int i = 0; i < 2; ++i) {
        int r = row0 + G.wm * 32 + i * 16 + G.quad * 4;
        #pragma unroll
        for (int j = 0; j < 2; ++j) {
            int c = col0 + G.wn * 32 + j * 16 + G.l16;
            float bv = bias[c];
            #pragma unroll
            for (int g2 = 0; g2 < 4; ++g2) {
                float v = tanh_fast(acc[i][j][g2] + bv);
                outp[(size_t)(r + g2) * UNITS + c] = (_Float16)v;
            }
        }
    }
}

// ---------------- persistent cooperative kernel ----------------

struct Params {
    const int* x;
    const _Float16* EMBP; const _Float16* W0XT; const _Float16* W0HT;
    const _Float16* W1XT; const _Float16* W1HT;
    const float* b0; const float* b1; const float* Wout; const float* bout;
    _Float16* H0a; _Float16* H0b; _Float16* H1a; _Float16* H1b;
    float* out;
    unsigned* bar;
};

__device__ __forceinline__ void grid_barrier(unsigned* bar) {
    __syncthreads();
    if (threadIdx.x == 0) {
        __threadfence();   // release: make H stores device-visible
        unsigned g = __hip_atomic_load(&bar[1], __ATOMIC_ACQUIRE, __HIP_MEMORY_SCOPE_AGENT);
        unsigned old = __hip_atomic_fetch_add(&bar[0], 1u, __ATOMIC_ACQ_REL, __HIP_MEMORY_SCOPE_AGENT);
        if (old == NBLK - 1) {
            __hip_atomic_store(&bar[0], 0u, __ATOMIC_RELAXED, __HIP_MEMORY_SCOPE_AGENT);
            __hip_atomic_store(&bar[1], g + 1u, __ATOMIC_RELEASE, __HIP_MEMORY_SCOPE_AGENT);
        } else {
            while (__hip_atomic_load(&bar[1], __ATOMIC_ACQUIRE, __HIP_MEMORY_SCOPE_AGENT) == g)
                __builtin_amdgcn_s_sleep(2);
        }
        __threadfence();   // acquire: invalidate stale cached H lines
    }
    __syncthreads();
}

__launch_bounds__(256, 2)
__global__ void rnn_kernel(Params P) {
    __shared__ _Float16 As[64 * KC];   // 16 KB
    __shared__ _Float16 Bs[64 * KC];   // 16 KB
    TileGeom G = make_geom(threadIdx.x);

    int bid = blockIdx.x;
    int xcd = bid & 7, g = bid >> 3;
    int role = g >> 5, gg = g & 31;                 // role 0: layer1(t), 1: layer0(t+1)
    int j = (xcd << 1) | (gg >> 4), i = gg & 15;    // XCD-local col slice
    int row0 = i * 64, col0 = j * 64;

    for (int phase = 0; phase <= SEQ; ++phase) {
        bool active = role ? (phase < SEQ) : (phase >= 1);
        if (active) {
            f4v acc[2][2] = {};
            if (role) {
                // layer0: h0_p = tanh(emb[x[:,p]] @ W0x + h0_{p-1} @ W0h + b0)
                int p = phase;
                const int* xi = P.x + p;
                const _Float16* A1 = (p & 1) ? P.H0a : P.H0b;
                _Float16* outp = (p & 1) ? P.H0b : P.H0a;
                gemm_chunk<true>(G, As, Bs, P.EMBP, EPAD, xi, P.W0XT, EPAD,
                                 row0, col0, 0, acc);
                if (p > 0)
                    for (int c = 0; c < UNITS / KC; ++c)
                        gemm_chunk<false>(G, As, Bs, A1, UNITS, nullptr, P.W0HT, UNITS,
                                          row0, col0, c * KC, acc);
                epilogue(G, acc, P.b0, outp, row0, col0);
            } else {
                // layer1: h1_p = tanh(h0_p @ W1x + h1_{p-1} @ W1h + b1)
                int p = phase - 1;
                const _Float16* A0 = (p & 1) ? P.H0b : P.H0a;
                const _Float16* A1 = (p & 1) ? P.H1a : P.H1b;
                _Float16* outp = (p & 1) ? P.H1b : P.H1a;
                for (int c = 0; c < UNITS / KC; ++c)
                    gemm_chunk<false>(G, As, Bs, A0, UNITS, nullptr, P.W1XT, UNITS,
                                      row0, col0, c * KC, acc);
                if (p > 0)
                    for (int c = 0; c < UNITS / KC; ++c)
                        gemm_chunk<false>(G, As, Bs, A1, UNITS, nullptr, P.W1HT, UNITS,
                                          row0, col0, c * KC, acc);
                epilogue(G, acc, P.b1, outp, row0, col0);
            }
        }
        grid_barrier(P.bar);
    }

    // out[b] = sigmoid(h1_79[b]·Wout + bout); h1_79 in H1b (p=79 odd)
    if (bid < 256) {
        int row = bid * 4 + G.w;
        const _Float16* hr = P.H1b + (size_t)row * UNITS;
        float sacc = 0.f;
        #pragma unroll
        for (int it = 0; it < 16; ++it)
            sacc += (float)hr[it * 64 + G.lane] * P.Wout[it * 64 + G.lane];
        #pragma unroll
        for (int off = 32; off; off >>= 1) sacc += __shfl_down(sacc, off);
        if (G.lane == 0) P.out[row] = 1.f / (1.f + __expf(-(sacc + P.bout[0])));
    }
}

// ---------------- fallback: proven 81-launch path (R3) ----------------

struct GemmTask {
    const _Float16* A0; const _Float16* B0T;
    const int* xidx;
    int nch0, lda0, ldb0;
    const _Float16* A1; const _Float16* B1T;
    const float* bias; _Float16* out;
};

__launch_bounds__(256)
__global__ void step_kernel(GemmTask Ta, GemmTask Tb) {
    GemmTask T = (blockIdx.z == 0) ? Ta : Tb;
    __shared__ _Float16 As[64 * KC];
    __shared__ _Float16 Bs[64 * KC];
    TileGeom G = make_geom(threadIdx.x);
    int row0 = blockIdx.y * 64, col0 = blockIdx.x * 64;
    f4v acc[2][2] = {};

    if (T.xidx)
        gemm_chunk<true>(G, As, Bs, T.A0, T.lda0, T.xidx, T.B0T, T.ldb0,
                         row0, col0, 0, acc);
    else
        for (int c = 0; c < T.nch0; ++c)
            gemm_chunk<false>(G, As, Bs, T.A0, T.lda0, nullptr, T.B0T, T.ldb0,
                              row0, col0, c * KC, acc);
    if (T.A1)
        for (int c = 0; c < UNITS / KC; ++c)
            gemm_chunk<false>(G, As, Bs, T.A1, UNITS, nullptr, T.B1T, UNITS,
                              row0, col0, c * KC, acc);
    epilogue(G, acc, T.bias, T.out, row0, col0);
}

__global__ void out_kernel(const _Float16* __restrict__ h1, const float* __restrict__ wout,
                           const float* __restrict__ bout, float* __restrict__ out) {
    int row  = blockIdx.x * 4 + (threadIdx.x >> 6);
    int lane = threadIdx.x & 63;
    const _Float16* hr = h1 + (size_t)row * UNITS;
    float sacc = 0.f;
    #pragma unroll
    for (int i = 0; i < 16; ++i)
        sacc += (float)hr[i * 64 + lane] * wout[i * 64 + lane];
    #pragma unroll
    for (int off = 32; off; off >>= 1) sacc += __shfl_down(sacc, off);
    if (lane == 0) out[row] = 1.f / (1.f + __expf(-(sacc + bout[0])));
}

// ---------------- launch ----------------

extern "C" void kernel_launch(void* const* d_in, const int* in_sizes, int n_in,
                              void* d_out, int out_size, void* d_ws, size_t ws_size,
                              hipStream_t stream) {
    const int*   x    = (const int*)d_in[0];
    const float* emb  = (const float*)d_in[1];
    const float* W0x  = (const float*)d_in[2];
    const float* W0h  = (const float*)d_in[3];
    const float* b0   = (const float*)d_in[4];
    const float* W1x  = (const float*)d_in[5];
    const float* W1h  = (const float*)d_in[6];
    const float* b1   = (const float*)d_in[7];
    const float* Wout = (const float*)d_in[8];
    const float* bout = (const float*)d_in[9];
    float* out = (float*)d_out;

    char* ws = (char*)d_ws;
    _Float16* EMBP = (_Float16*)ws;                     // 10000*128*2 = 2,560,000
    _Float16* W0XT = (_Float16*)(ws + 2560000);         // 1024*128*2  =   262,144
    _Float16* W0HT = (_Float16*)(ws + 2822144);         // 2 MB
    _Float16* W1XT = (_Float16*)(ws + 4919296);         // 2 MB
    _Float16* W1HT = (_Float16*)(ws + 7016448);         // 2 MB
    _Float16* Hbuf = (_Float16*)(ws + 9113600);         // 4 x 2 MB
    unsigned* bar  = (unsigned*)(ws + 17502208);        // 64 B
    _Float16* H0a = Hbuf;
    _Float16* H0b = Hbuf + 1024 * 1024;
    _Float16* H1a = Hbuf + 2 * 1024 * 1024;
    _Float16* H1b = Hbuf + 3 * 1024 * 1024;

    embp_kernel<<<10000, EPAD, 0, stream>>>(emb, EMBP);
    tpad_kernel<<<dim3(4, 32),  dim3(32, 8), 0, stream>>>(W0x, W0XT, EMBD, EPAD, UNITS);
    tpad_kernel<<<dim3(32, 32), dim3(32, 8), 0, stream>>>(W0h, W0HT, UNITS, UNITS, UNITS);
    tpad_kernel<<<dim3(32, 32), dim3(32, 8), 0, stream>>>(W1x, W1XT, UNITS, UNITS, UNITS);
    tpad_kernel<<<dim3(32, 32), dim3(32, 8), 0, stream>>>(W1h, W1HT, UNITS, UNITS, UNITS);
    zero_kernel<<<2048, 256, 0, stream>>>((s8v*)Hbuf);
    hipMemsetAsync(bar, 0, 64, stream);

    Params P;
    P.x = x; P.EMBP = EMBP; P.W0XT = W0XT; P.W0HT = W0HT; P.W1XT = W1XT; P.W1HT = W1HT;
    P.b0 = b0; P.b1 = b1; P.Wout = Wout; P.bout = bout;
    P.H0a = H0a; P.H0b = H0b; P.H1a = H1a; P.H1b = H1b;
    P.out = out; P.bar = bar;
    void* kargs[] = { &P };
    hipError_t err = hipLaunchCooperativeKernel(
        reinterpret_cast<void*>(rnn_kernel), dim3(NBLK), dim3(256), kargs, 0, stream);

    if (err != hipSuccess) {
        (void)hipGetLastError();   // clear error state; run proven fallback
        GemmTask p;
        p.A0 = EMBP; p.B0T = W0XT; p.xidx = x; p.nch0 = 1; p.lda0 = EPAD; p.ldb0 = EPAD;
        p.A1 = nullptr; p.B1T = nullptr; p.bias = b0; p.out = H0a;
        step_kernel<<<dim3(16, 16, 1), 256, 0, stream>>>(p, p);
        for (int t = 0; t < SEQ; ++t) {
            _Float16* h0cur = (t & 1) ? H0b : H0a;
            GemmTask l1;
            l1.A0 = h0cur; l1.B0T = W1XT; l1.xidx = nullptr;
            l1.nch0 = UNITS / KC; l1.lda0 = UNITS; l1.ldb0 = UNITS;
            l1.A1 = (t == 0) ? nullptr : ((t & 1) ? H1a : H1b);
            l1.B1T = W1HT; l1.bias = b1; l1.out = (t & 1) ? H1b : H1a;
            if (t < SEQ - 1) {
                GemmTask l0;
                l0.A0 = EMBP; l0.B0T = W0XT; l0.xidx = x + (t + 1);
                l0.nch0 = 1; l0.lda0 = EPAD; l0.ldb0 = EPAD;
                l0.A1 = h0cur; l0.B1T = W0HT; l0.bias = b0;
                l0.out = (t & 1) ? H0a : H0b;
                step_kernel<<<dim3(16, 16, 2), 256, 0, stream>>>(l1, l0);
            } else {
                step_kernel<<<dim3(16, 16, 1), 256, 0, stream>>>(l1, l1);
            }
        }
        out_kernel<<<256, 256, 0, stream>>>(H1b, Wout, bout, out);
    }
}

// Round 6
// 4599.290 us; speedup vs baseline: 2.0502x; 2.0502x over previous
//
#include <hip/hip_runtime.h>

// MyRnn persistent v3: whole 80-step 2-layer RNN in ONE cooperative kernel.
// R6 change vs R5: hierarchical sense-reversing grid barrier with RELAXED polls
// (R5's per-poll ACQUIRE loads caused an L2-invalidate storm: 106 us/phase).
// Compute path identical to R5 (proven correct, ~10 us/phase).

typedef _Float16 h8v __attribute__((ext_vector_type(8)));
typedef float    f4v __attribute__((ext_vector_type(4)));
typedef short    s8v __attribute__((ext_vector_type(8)));

#define UNITS 1024
#define SEQ   80
#define EMBD  100
#define EPAD  128
#define KC    128
#define NBLK  512

__device__ __forceinline__ float tanh_fast(float x) {
    x = fminf(15.f, fmaxf(-15.f, x));   // also scrubs NaN
    float e = __expf(2.f * x);
    return (e - 1.f) / (e + 1.f);
}

__device__ __forceinline__ void gl_lds16(const _Float16* g, _Float16* l) {
    __builtin_amdgcn_global_load_lds(
        (const __attribute__((address_space(1))) void*)g,
        (__attribute__((address_space(3))) void*)l, 16, 0, 0);
}

// ---------------- prep kernels ----------------

__global__ void embp_kernel(const float* __restrict__ emb, _Float16* __restrict__ embp) {
    int r = blockIdx.x, k = threadIdx.x;
    embp[r * EPAD + k] = (k < EMBD) ? (_Float16)emb[r * EMBD + k] : (_Float16)0.f;
}

__global__ void tpad_kernel(const float* __restrict__ w, _Float16* __restrict__ wt,
                            int K, int Kpad, int N) {
    __shared__ float t[32][33];
    int k0 = blockIdx.x * 32, n0 = blockIdx.y * 32;
    int tx = threadIdx.x, ty = threadIdx.y;
    for (int i = ty; i < 32; i += 8) {
        int k = k0 + i;
        t[i][tx] = (k < K) ? w[(size_t)k * N + n0 + tx] : 0.f;
    }
    __syncthreads();
    for (int i = ty; i < 32; i += 8)
        wt[(size_t)(n0 + i) * Kpad + k0 + tx] = (_Float16)t[tx][i];
}

__global__ void zero_kernel(s8v* __restrict__ p) {
    p[blockIdx.x * 256 + threadIdx.x] = (s8v)0;
}

// ---------------- shared GEMM tile code (KC=128, proven R3/R5) ----------------

struct TileGeom {
    int rq[4], ldsoff[4], koff[4];
    int lane, w, wm, wn, quad, l16;
};

__device__ __forceinline__ TileGeom make_geom(int tid) {
    TileGeom G;
    G.lane = tid & 63; G.w = tid >> 6;
    G.wm = G.w >> 1;   G.wn = G.w & 1;
    G.quad = G.lane >> 4; G.l16 = G.lane & 15;
    #pragma unroll
    for (int q = 0; q < 4; ++q) {
        int g = G.w * 4 + q;
        int r = g * 4 + (G.lane >> 4);
        G.rq[q] = r;
        G.ldsoff[q] = g * 512;
        G.koff[q] = 8 * ((G.lane & 15) ^ (r & 7));
    }
    return G;
}

template <bool GATHER>
__device__ __forceinline__ void gemm_chunk(
    const TileGeom& G, _Float16* As, _Float16* Bs,
    const _Float16* A, int lda, const int* xi,
    const _Float16* Bt, int ldb, int row0, int col0, int k0, f4v acc[2][2]) {
    #pragma unroll
    for (int q = 0; q < 4; ++q) {
        int r = G.rq[q];
        const _Float16* ap;
        if (GATHER)
            ap = A + (size_t)xi[(size_t)(row0 + r) * SEQ] * EPAD + k0 + G.koff[q];
        else
            ap = A + (size_t)(row0 + r) * lda + k0 + G.koff[q];
        const _Float16* bp = Bt + (size_t)(col0 + r) * ldb + k0 + G.koff[q];
        gl_lds16(ap, As + G.ldsoff[q]);
        gl_lds16(bp, Bs + G.ldsoff[q]);
    }
    __syncthreads();
    #pragma unroll
    for (int kk = 0; kk < 4; ++kk) {
        int us = 8 * ((kk * 4 + G.quad) ^ (G.l16 & 7));
        h8v af[2], bf[2];
        #pragma unroll
        for (int i = 0; i < 2; ++i)
            af[i] = *(const h8v*)(As + (G.wm * 32 + i * 16 + G.l16) * KC + us);
        #pragma unroll
        for (int j = 0; j < 2; ++j)
            bf[j] = *(const h8v*)(Bs + (G.wn * 32 + j * 16 + G.l16) * KC + us);
        #pragma unroll
        for (int i = 0; i < 2; ++i)
            #pragma unroll
            for (int j = 0; j < 2; ++j)
                acc[i][j] = __builtin_amdgcn_mfma_f32_16x16x32_f16(
                    af[i], bf[j], acc[i][j], 0, 0, 0);
    }
    __syncthreads();
}

__device__ __forceinline__ void epilogue(
    const TileGeom& G, f4v acc[2][2], const float* bias, _Float16* outp,
    int row0, int col0) {
    #pragma unroll
    for (int i = 0; i < 2; ++i) {
        int r = row0 + G.wm * 32 + i * 16 + G.quad * 4;
        #pragma unroll
        for (int j = 0; j < 2; ++j) {
            int c = col0 + G.wn * 32 + j * 16 + G.l16;
            float bv = bias[c];
            #pragma unroll
            for (int g2 = 0; g2 < 4; ++g2) {
                float v = tanh_fast(acc[i][j][g2] + bv);
                outp[(size_t)(r + g2) * UNITS + c] = (_Float16)v;
            }
        }
    }
}

// ---------------- persistent cooperative kernel ----------------

struct Params {
    const int* x;
    const _Float16* EMBP; const _Float16* W0XT; const _Float16* W0HT;
    const _Float16* W1XT; const _Float16* W1HT;
    const float* b0; const float* b1; const float* Wout; const float* bout;
    _Float16* H0a; _Float16* H0b; _Float16* H1a; _Float16* H1b;
    float* out;
    unsigned* bar;   // words: [grp*32] x8 group ctrs (128B apart), [256] root, [288] gen
};

__device__ __forceinline__ void grid_barrier(unsigned* bar, int bid) {
    __syncthreads();
    if (threadIdx.x == 0) {
        __threadfence();   // release: make H stores agent-visible
        unsigned g = __hip_atomic_load(&bar[288], __ATOMIC_RELAXED, __HIP_MEMORY_SCOPE_AGENT);
        int grp = bid & 7;
        unsigned old = __hip_atomic_fetch_add(&bar[grp * 32], 1u,
                           __ATOMIC_ACQ_REL, __HIP_MEMORY_SCOPE_AGENT);
        bool flipped = false;
        if (old == (NBLK / 8) - 1) {                 // last in group
            __hip_atomic_store(&bar[grp * 32], 0u, __ATOMIC_RELAXED, __HIP_MEMORY_SCOPE_AGENT);
            unsigned o2 = __hip_atomic_fetch_add(&bar[256], 1u,
                              __ATOMIC_ACQ_REL, __HIP_MEMORY_SCOPE_AGENT);
            if (o2 == 7) {                           // last group
                __hip_atomic_store(&bar[256], 0u, __ATOMIC_RELAXED, __HIP_MEMORY_SCOPE_AGENT);
                __hip_atomic_store(&bar[288], g + 1u, __ATOMIC_RELEASE, __HIP_MEMORY_SCOPE_AGENT);
                flipped = true;
            }
        }
        if (!flipped)
            while (__hip_atomic_load(&bar[288], __ATOMIC_RELAXED, __HIP_MEMORY_SCOPE_AGENT) == g)
                __builtin_amdgcn_s_sleep(4);         // RELAXED poll: no invalidate storm
        __threadfence();   // acquire: one invalidate per block per phase
    }
    __syncthreads();
}

__launch_bounds__(256, 2)
__global__ void rnn_kernel(Params P) {
    __shared__ _Float16 As[64 * KC];   // 16 KB
    __shared__ _Float16 Bs[64 * KC];   // 16 KB
    TileGeom G = make_geom(threadIdx.x);

    int bid = blockIdx.x;
    int xcd = bid & 7, g = bid >> 3;
    int role = g >> 5, gg = g & 31;                 // role 0: layer1(t), 1: layer0(t+1)
    int j = (xcd << 1) | (gg >> 4), i = gg & 15;    // XCD-local col slice
    int row0 = i * 64, col0 = j * 64;

    for (int phase = 0; phase <= SEQ; ++phase) {
        bool active = role ? (phase < SEQ) : (phase >= 1);
        if (active) {
            f4v acc[2][2] = {};
            if (role) {
                // layer0: h0_p = tanh(emb[x[:,p]] @ W0x + h0_{p-1} @ W0h + b0)
                int p = phase;
                const int* xi = P.x + p;
                const _Float16* A1 = (p & 1) ? P.H0a : P.H0b;
                _Float16* outp = (p & 1) ? P.H0b : P.H0a;
                gemm_chunk<true>(G, As, Bs, P.EMBP, EPAD, xi, P.W0XT, EPAD,
                                 row0, col0, 0, acc);
                if (p > 0)
                    for (int c = 0; c < UNITS / KC; ++c)
                        gemm_chunk<false>(G, As, Bs, A1, UNITS, nullptr, P.W0HT, UNITS,
                                          row0, col0, c * KC, acc);
                epilogue(G, acc, P.b0, outp, row0, col0);
            } else {
                // layer1: h1_p = tanh(h0_p @ W1x + h1_{p-1} @ W1h + b1)
                int p = phase - 1;
                const _Float16* A0 = (p & 1) ? P.H0b : P.H0a;
                const _Float16* A1 = (p & 1) ? P.H1a : P.H1b;
                _Float16* outp = (p & 1) ? P.H1b : P.H1a;
                for (int c = 0; c < UNITS / KC; ++c)
                    gemm_chunk<false>(G, As, Bs, A0, UNITS, nullptr, P.W1XT, UNITS,
                                      row0, col0, c * KC, acc);
                if (p > 0)
                    for (int c = 0; c < UNITS / KC; ++c)
                        gemm_chunk<false>(G, As, Bs, A1, UNITS, nullptr, P.W1HT, UNITS,
                                          row0, col0, c * KC, acc);
                epilogue(G, acc, P.b1, outp, row0, col0);
            }
        }
        grid_barrier(P.bar, bid);
    }

    // out[b] = sigmoid(h1_79[b]·Wout + bout); h1_79 in H1b (p=79 odd)
    if (bid < 256) {
        int row = bid * 4 + G.w;
        const _Float16* hr = P.H1b + (size_t)row * UNITS;
        float sacc = 0.f;
        #pragma unroll
        for (int it = 0; it < 16; ++it)
            sacc += (float)hr[it * 64 + G.lane] * P.Wout[it * 64 + G.lane];
        #pragma unroll
        for (int off = 32; off; off >>= 1) sacc += __shfl_down(sacc, off);
        if (G.lane == 0) P.out[row] = 1.f / (1.f + __expf(-(sacc + P.bout[0])));
    }
}

// ---------------- fallback: proven 81-launch path (R3) ----------------

struct GemmTask {
    const _Float16* A0; const _Float16* B0T;
    const int* xidx;
    int nch0, lda0, ldb0;
    const _Float16* A1; const _Float16* B1T;
    const float* bias; _Float16* out;
};

__launch_bounds__(256)
__global__ void step_kernel(GemmTask Ta, GemmTask Tb) {
    GemmTask T = (blockIdx.z == 0) ? Ta : Tb;
    __shared__ _Float16 As[64 * KC];
    __shared__ _Float16 Bs[64 * KC];
    TileGeom G = make_geom(threadIdx.x);
    int row0 = blockIdx.y * 64, col0 = blockIdx.x * 64;
    f4v acc[2][2] = {};

    if (T.xidx)
        gemm_chunk<true>(G, As, Bs, T.A0, T.lda0, T.xidx, T.B0T, T.ldb0,
                         row0, col0, 0, acc);
    else
        for (int c = 0; c < T.nch0; ++c)
            gemm_chunk<false>(G, As, Bs, T.A0, T.lda0, nullptr, T.B0T, T.ldb0,
                              row0, col0, c * KC, acc);
    if (T.A1)
        for (int c = 0; c < UNITS / KC; ++c)
            gemm_chunk<false>(G, As, Bs, T.A1, UNITS, nullptr, T.B1T, UNITS,
                              row0, col0, c * KC, acc);
    epilogue(G, acc, T.bias, T.out, row0, col0);
}

__global__ void out_kernel(const _Float16* __restrict__ h1, const float* __restrict__ wout,
                           const float* __restrict__ bout, float* __restrict__ out) {
    int row  = blockIdx.x * 4 + (threadIdx.x >> 6);
    int lane = threadIdx.x & 63;
    const _Float16* hr = h1 + (size_t)row * UNITS;
    float sacc = 0.f;
    #pragma unroll
    for (int i = 0; i < 16; ++i)
        sacc += (float)hr[i * 64 + lane] * wout[i * 64 + lane];
    #pragma unroll
    for (int off = 32; off; off >>= 1) sacc += __shfl_down(sacc, off);
    if (lane == 0) out[row] = 1.f / (1.f + __expf(-(sacc + bout[0])));
}

// ---------------- launch ----------------

extern "C" void kernel_launch(void* const* d_in, const int* in_sizes, int n_in,
                              void* d_out, int out_size, void* d_ws, size_t ws_size,
                              hipStream_t stream) {
    const int*   x    = (const int*)d_in[0];
    const float* emb  = (const float*)d_in[1];
    const float* W0x  = (const float*)d_in[2];
    const float* W0h  = (const float*)d_in[3];
    const float* b0   = (const float*)d_in[4];
    const float* W1x  = (const float*)d_in[5];
    const float* W1h  = (const float*)d_in[6];
    const float* b1   = (const float*)d_in[7];
    const float* Wout = (const float*)d_in[8];
    const float* bout = (const float*)d_in[9];
    float* out = (float*)d_out;

    char* ws = (char*)d_ws;
    _Float16* EMBP = (_Float16*)ws;                     // 10000*128*2 = 2,560,000
    _Float16* W0XT = (_Float16*)(ws + 2560000);         // 1024*128*2  =   262,144
    _Float16* W0HT = (_Float16*)(ws + 2822144);         // 2 MB
    _Float16* W1XT = (_Float16*)(ws + 4919296);         // 2 MB
    _Float16* W1HT = (_Float16*)(ws + 7016448);         // 2 MB
    _Float16* Hbuf = (_Float16*)(ws + 9113600);         // 4 x 2 MB
    unsigned* bar  = (unsigned*)(ws + 17502208);        // 2 KB barrier region
    _Float16* H0a = Hbuf;
    _Float16* H0b = Hbuf + 1024 * 1024;
    _Float16* H1a = Hbuf + 2 * 1024 * 1024;
    _Float16* H1b = Hbuf + 3 * 1024 * 1024;

    embp_kernel<<<10000, EPAD, 0, stream>>>(emb, EMBP);
    tpad_kernel<<<dim3(4, 32),  dim3(32, 8), 0, stream>>>(W0x, W0XT, EMBD, EPAD, UNITS);
    tpad_kernel<<<dim3(32, 32), dim3(32, 8), 0, stream>>>(W0h, W0HT, UNITS, UNITS, UNITS);
    tpad_kernel<<<dim3(32, 32), dim3(32, 8), 0, stream>>>(W1x, W1XT, UNITS, UNITS, UNITS);
    tpad_kernel<<<dim3(32, 32), dim3(32, 8), 0, stream>>>(W1h, W1HT, UNITS, UNITS, UNITS);
    zero_kernel<<<2048, 256, 0, stream>>>((s8v*)Hbuf);
    hipMemsetAsync(bar, 0, 2048, stream);

    Params P;
    P.x = x; P.EMBP = EMBP; P.W0XT = W0XT; P.W0HT = W0HT; P.W1XT = W1XT; P.W1HT = W1HT;
    P.b0 = b0; P.b1 = b1; P.Wout = Wout; P.bout = bout;
    P.H0a = H0a; P.H0b = H0b; P.H1a = H1a; P.H1b = H1b;
    P.out = out; P.bar = bar;
    void* kargs[] = { &P };
    hipError_t err = hipLaunchCooperativeKernel(
        reinterpret_cast<void*>(rnn_kernel), dim3(NBLK), dim3(256), kargs, 0, stream);

    if (err != hipSuccess) {
        (void)hipGetLastError();   // clear error state; run proven fallback
        GemmTask p;
        p.A0 = EMBP; p.B0T = W0XT; p.xidx = x; p.nch0 = 1; p.lda0 = EPAD; p.ldb0 = EPAD;
        p.A1 = nullptr; p.B1T = nullptr; p.bias = b0; p.out = H0a;
        step_kernel<<<dim3(16, 16, 1), 256, 0, stream>>>(p, p);
        for (int t = 0; t < SEQ; ++t) {
            _Float16* h0cur = (t & 1) ? H0b : H0a;
            GemmTask l1;
            l1.A0 = h0cur; l1.B0T = W1XT; l1.xidx = nullptr;
            l1.nch0 = UNITS / KC; l1.lda0 = UNITS; l1.ldb0 = UNITS;
            l1.A1 = (t == 0) ? nullptr : ((t & 1) ? H1a : H1b);
            l1.B1T = W1HT; l1.bias = b1; l1.out = (t & 1) ? H1b : H1a;
            if (t < SEQ - 1) {
                GemmTask l0;
                l0.A0 = EMBP; l0.B0T = W0XT; l0.xidx = x + (t + 1);
                l0.nch0 = 1; l0.lda0 = EPAD; l0.ldb0 = EPAD;
                l0.A1 = h0cur; l0.B1T = W0HT; l0.bias = b0;
                l0.out = (t & 1) ? H0a : H0b;
                step_kernel<<<dim3(16, 16, 2), 256, 0, stream>>>(l1, l0);
            } else {
                step_kernel<<<dim3(16, 16, 1), 256, 0, stream>>>(l1, l1);
            }
        }
        out_kernel<<<256, 256, 0, stream>>>(H1b, Wout, bout, out);
    }
}

// Round 7
// 2526.687 us; speedup vs baseline: 3.7319x; 1.8203x over previous
//
#include <hip/hip_runtime.h>

// MyRnn persistent v4: fence-free coherence.
// R7 change vs R6: no __threadfence in grid barrier (R6's per-phase agent
// fences invalidated every XCD L2 -> 21 MB refetch/phase, 46 of 56 us/phase).
// Instead: H ping-pong buffers are written with agent-scope atomic stores
// (sc0 sc1, write-through to IC) and staged with global_load_lds aux=17
// (sc0|sc1: read from coherence point, bypass stale L1/L2 without
// invalidating). Weights/EMBP stay normally cached -> L2-resident across
// all 80 phases.

typedef _Float16 h8v __attribute__((ext_vector_type(8)));
typedef float    f4v __attribute__((ext_vector_type(4)));
typedef short    s8v __attribute__((ext_vector_type(8)));

#define UNITS 1024
#define SEQ   80
#define EMBD  100
#define EPAD  128
#define KC    128
#define NBLK  512

__device__ __forceinline__ float tanh_fast(float x) {
    x = fminf(15.f, fmaxf(-15.f, x));   // also scrubs NaN
    float e = __expf(2.f * x);
    return (e - 1.f) / (e + 1.f);
}

template <int AUX>
__device__ __forceinline__ void gl_lds16(const _Float16* g, _Float16* l) {
    __builtin_amdgcn_global_load_lds(
        (const __attribute__((address_space(1))) void*)g,
        (__attribute__((address_space(3))) void*)l, 16, 0, AUX);
}

// coherent (IC-visible) 2-byte store/load for H data
__device__ __forceinline__ void h_store(_Float16* p, float v) {
    _Float16 h = (_Float16)v;
    __hip_atomic_store((short*)p, __builtin_bit_cast(short, h),
                       __ATOMIC_RELAXED, __HIP_MEMORY_SCOPE_AGENT);
}
__device__ __forceinline__ float h_load(const _Float16* p) {
    short s = __hip_atomic_load((const short*)p, __ATOMIC_RELAXED,
                                __HIP_MEMORY_SCOPE_AGENT);
    return (float)__builtin_bit_cast(_Float16, s);
}

// ---------------- prep kernels ----------------

__global__ void embp_kernel(const float* __restrict__ emb, _Float16* __restrict__ embp) {
    int r = blockIdx.x, k = threadIdx.x;
    embp[r * EPAD + k] = (k < EMBD) ? (_Float16)emb[r * EMBD + k] : (_Float16)0.f;
}

__global__ void tpad_kernel(const float* __restrict__ w, _Float16* __restrict__ wt,
                            int K, int Kpad, int N) {
    __shared__ float t[32][33];
    int k0 = blockIdx.x * 32, n0 = blockIdx.y * 32;
    int tx = threadIdx.x, ty = threadIdx.y;
    for (int i = ty; i < 32; i += 8) {
        int k = k0 + i;
        t[i][tx] = (k < K) ? w[(size_t)k * N + n0 + tx] : 0.f;
    }
    __syncthreads();
    for (int i = ty; i < 32; i += 8)
        wt[(size_t)(n0 + i) * Kpad + k0 + tx] = (_Float16)t[tx][i];
}

__global__ void zero_kernel(s8v* __restrict__ p) {
    p[blockIdx.x * 256 + threadIdx.x] = (s8v)0;
}

// ---------------- shared GEMM tile code (KC=128) ----------------

struct TileGeom {
    int rq[4], ldsoff[4], koff[4];
    int lane, w, wm, wn, quad, l16;
};

__device__ __forceinline__ TileGeom make_geom(int tid) {
    TileGeom G;
    G.lane = tid & 63; G.w = tid >> 6;
    G.wm = G.w >> 1;   G.wn = G.w & 1;
    G.quad = G.lane >> 4; G.l16 = G.lane & 15;
    #pragma unroll
    for (int q = 0; q < 4; ++q) {
        int g = G.w * 4 + q;
        int r = g * 4 + (G.lane >> 4);
        G.rq[q] = r;
        G.ldsoff[q] = g * 512;
        G.koff[q] = 8 * ((G.lane & 15) ^ (r & 7));
    }
    return G;
}

// AUXA: cache policy for A staging (0 = cached weights/emb, 17 = sc0|sc1 H)
template <bool GATHER, int AUXA>
__device__ __forceinline__ void gemm_chunk(
    const TileGeom& G, _Float16* As, _Float16* Bs,
    const _Float16* A, int lda, const int* xi,
    const _Float16* Bt, int ldb, int row0, int col0, int k0, f4v acc[2][2]) {
    #pragma unroll
    for (int q = 0; q < 4; ++q) {
        int r = G.rq[q];
        const _Float16* ap;
        if (GATHER)
            ap = A + (size_t)xi[(size_t)(row0 + r) * SEQ] * EPAD + k0 + G.koff[q];
        else
            ap = A + (size_t)(row0 + r) * lda + k0 + G.koff[q];
        const _Float16* bp = Bt + (size_t)(col0 + r) * ldb + k0 + G.koff[q];
        gl_lds16<AUXA>(ap, As + G.ldsoff[q]);
        gl_lds16<0>(bp, Bs + G.ldsoff[q]);
    }
    __syncthreads();
    #pragma unroll
    for (int kk = 0; kk < 4; ++kk) {
        int us = 8 * ((kk * 4 + G.quad) ^ (G.l16 & 7));
        h8v af[2], bf[2];
        #pragma unroll
        for (int i = 0; i < 2; ++i)
            af[i] = *(const h8v*)(As + (G.wm * 32 + i * 16 + G.l16) * KC + us);
        #pragma unroll
        for (int j = 0; j < 2; ++j)
            bf[j] = *(const h8v*)(Bs + (G.wn * 32 + j * 16 + G.l16) * KC + us);
        #pragma unroll
        for (int i = 0; i < 2; ++i)
            #pragma unroll
            for (int j = 0; j < 2; ++j)
                acc[i][j] = __builtin_amdgcn_mfma_f32_16x16x32_f16(
                    af[i], bf[j], acc[i][j], 0, 0, 0);
    }
    __syncthreads();
}

// epilogue writes H via coherent stores (agent-scope, write-through IC)
__device__ __forceinline__ void epilogue(
    const TileGeom& G, f4v acc[2][2], const float* bias, _Float16* outp,
    int row0, int col0) {
    #pragma unroll
    for (int i = 0; i < 2; ++i) {
        int r = row0 + G.wm * 32 + i * 16 + G.quad * 4;
        #pragma unroll
        for (int j = 0; j < 2; ++j) {
            int c = col0 + G.wn * 32 + j * 16 + G.l16;
            float bv = bias[c];
            #pragma unroll
            for (int g2 = 0; g2 < 4; ++g2) {
                float v = tanh_fast(acc[i][j][g2] + bv);
                h_store(outp + (size_t)(r + g2) * UNITS + c, v);
            }
        }
    }
}

// ---------------- persistent cooperative kernel ----------------

struct Params {
    const int* x;
    const _Float16* EMBP; const _Float16* W0XT; const _Float16* W0HT;
    const _Float16* W1XT; const _Float16* W1HT;
    const float* b0; const float* b1; const float* Wout; const float* bout;
    _Float16* H0a; _Float16* H0b; _Float16* H1a; _Float16* H1b;
    float* out;
    unsigned* bar;   // words: [grp*32] x8 group ctrs (128B apart), [256] root, [288] gen
};

// fence-free: H coherence is handled by sc0/sc1 data ops; the ACQ_REL arrive
// chain orders the flag itself.
__device__ __forceinline__ void grid_barrier(unsigned* bar, int bid) {
    __syncthreads();
    if (threadIdx.x == 0) {
        unsigned g = __hip_atomic_load(&bar[288], __ATOMIC_RELAXED, __HIP_MEMORY_SCOPE_AGENT);
        int grp = bid & 7;
        unsigned old = __hip_atomic_fetch_add(&bar[grp * 32], 1u,
                           __ATOMIC_ACQ_REL, __HIP_MEMORY_SCOPE_AGENT);
        bool flipped = false;
        if (old == (NBLK / 8) - 1) {
            __hip_atomic_store(&bar[grp * 32], 0u, __ATOMIC_RELAXED, __HIP_MEMORY_SCOPE_AGENT);
            unsigned o2 = __hip_atomic_fetch_add(&bar[256], 1u,
                              __ATOMIC_ACQ_REL, __HIP_MEMORY_SCOPE_AGENT);
            if (o2 == 7) {
                __hip_atomic_store(&bar[256], 0u, __ATOMIC_RELAXED, __HIP_MEMORY_SCOPE_AGENT);
                __hip_atomic_store(&bar[288], g + 1u, __ATOMIC_RELEASE, __HIP_MEMORY_SCOPE_AGENT);
                flipped = true;
            }
        }
        if (!flipped)
            while (__hip_atomic_load(&bar[288], __ATOMIC_RELAXED, __HIP_MEMORY_SCOPE_AGENT) == g)
                __builtin_amdgcn_s_sleep(4);
    }
    __syncthreads();
}

__launch_bounds__(256, 2)
__global__ void rnn_kernel(Params P) {
    __shared__ _Float16 As[64 * KC];   // 16 KB
    __shared__ _Float16 Bs[64 * KC];   // 16 KB
    TileGeom G = make_geom(threadIdx.x);

    int bid = blockIdx.x;
    int xcd = bid & 7, g = bid >> 3;
    int role = g >> 5, gg = g & 31;                 // role 0: layer1(t), 1: layer0(t+1)
    int j = (xcd << 1) | (gg >> 4), i = gg & 15;    // XCD-local col slice
    int row0 = i * 64, col0 = j * 64;

    for (int phase = 0; phase <= SEQ; ++phase) {
        bool active = role ? (phase < SEQ) : (phase >= 1);
        if (active) {
            f4v acc[2][2] = {};
            if (role) {
                // layer0: h0_p = tanh(emb[x[:,p]] @ W0x + h0_{p-1} @ W0h + b0)
                int p = phase;
                const int* xi = P.x + p;
                const _Float16* A1 = (p & 1) ? P.H0a : P.H0b;
                _Float16* outp = (p & 1) ? P.H0b : P.H0a;
                gemm_chunk<true, 0>(G, As, Bs, P.EMBP, EPAD, xi, P.W0XT, EPAD,
                                    row0, col0, 0, acc);
                if (p > 0)
                    for (int c = 0; c < UNITS / KC; ++c)
                        gemm_chunk<false, 17>(G, As, Bs, A1, UNITS, nullptr, P.W0HT, UNITS,
                                              row0, col0, c * KC, acc);
                epilogue(G, acc, P.b0, outp, row0, col0);
            } else {
                // layer1: h1_p = tanh(h0_p @ W1x + h1_{p-1} @ W1h + b1)
                int p = phase - 1;
                const _Float16* A0 = (p & 1) ? P.H0b : P.H0a;
                const _Float16* A1 = (p & 1) ? P.H1a : P.H1b;
                _Float16* outp = (p & 1) ? P.H1b : P.H1a;
                for (int c = 0; c < UNITS / KC; ++c)
                    gemm_chunk<false, 17>(G, As, Bs, A0, UNITS, nullptr, P.W1XT, UNITS,
                                          row0, col0, c * KC, acc);
                if (p > 0)
                    for (int c = 0; c < UNITS / KC; ++c)
                        gemm_chunk<false, 17>(G, As, Bs, A1, UNITS, nullptr, P.W1HT, UNITS,
                                              row0, col0, c * KC, acc);
                epilogue(G, acc, P.b1, outp, row0, col0);
            }
        }
        grid_barrier(P.bar, bid);
    }

    // out[b] = sigmoid(h1_79[b]·Wout + bout); h1_79 in H1b (p=79 odd)
    if (bid < 256) {
        int row = bid * 4 + G.w;
        const _Float16* hr = P.H1b + (size_t)row * UNITS;
        float sacc = 0.f;
        #pragma unroll
        for (int it = 0; it < 16; ++it)
            sacc += h_load(hr + it * 64 + G.lane) * P.Wout[it * 64 + G.lane];
        #pragma unroll
        for (int off = 32; off; off >>= 1) sacc += __shfl_down(sacc, off);
        if (G.lane == 0) P.out[row] = 1.f / (1.f + __expf(-(sacc + P.bout[0])));
    }
}

// ---------------- fallback: proven 81-launch path ----------------

struct GemmTask {
    const _Float16* A0; const _Float16* B0T;
    const int* xidx;
    int nch0, lda0, ldb0;
    const _Float16* A1; const _Float16* B1T;
    const float* bias; _Float16* out;
};

__launch_bounds__(256)
__global__ void step_kernel(GemmTask Ta, GemmTask Tb) {
    GemmTask T = (blockIdx.z == 0) ? Ta : Tb;
    __shared__ _Float16 As[64 * KC];
    __shared__ _Float16 Bs[64 * KC];
    TileGeom G = make_geom(threadIdx.x);
    int row0 = blockIdx.y * 64, col0 = blockIdx.x * 64;
    f4v acc[2][2] = {};

    if (T.xidx)
        gemm_chunk<true, 0>(G, As, Bs, T.A0, T.lda0, T.xidx, T.B0T, T.ldb0,
                            row0, col0, 0, acc);
    else
        for (int c = 0; c < T.nch0; ++c)
            gemm_chunk<false, 17>(G, As, Bs, T.A0, T.lda0, nullptr, T.B0T, T.ldb0,
                                  row0, col0, c * KC, acc);
    if (T.A1)
        for (int c = 0; c < UNITS / KC; ++c)
            gemm_chunk<false, 17>(G, As, Bs, T.A1, UNITS, nullptr, T.B1T, UNITS,
                                  row0, col0, c * KC, acc);
    epilogue(G, acc, T.bias, T.out, row0, col0);
}

__global__ void out_kernel(const _Float16* __restrict__ h1, const float* __restrict__ wout,
                           const float* __restrict__ bout, float* __restrict__ out) {
    int row  = blockIdx.x * 4 + (threadIdx.x >> 6);
    int lane = threadIdx.x & 63;
    const _Float16* hr = h1 + (size_t)row * UNITS;
    float sacc = 0.f;
    #pragma unroll
    for (int i = 0; i < 16; ++i)
        sacc += h_load(hr + i * 64 + lane) * wout[i * 64 + lane];
    #pragma unroll
    for (int off = 32; off; off >>= 1) sacc += __shfl_down(sacc, off);
    if (lane == 0) out[row] = 1.f / (1.f + __expf(-(sacc + bout[0])));
}

// ---------------- launch ----------------

extern "C" void kernel_launch(void* const* d_in, const int* in_sizes, int n_in,
                              void* d_out, int out_size, void* d_ws, size_t ws_size,
                              hipStream_t stream) {
    const int*   x    = (const int*)d_in[0];
    const float* emb  = (const float*)d_in[1];
    const float* W0x  = (const float*)d_in[2];
    const float* W0h  = (const float*)d_in[3];
    const float* b0   = (const float*)d_in[4];
    const float* W1x  = (const float*)d_in[5];
    const float* W1h  = (const float*)d_in[6];
    const float* b1   = (const float*)d_in[7];
    const float* Wout = (const float*)d_in[8];
    const float* bout = (const float*)d_in[9];
    float* out = (float*)d_out;

    char* ws = (char*)d_ws;
    _Float16* EMBP = (_Float16*)ws;                     // 10000*128*2 = 2,560,000
    _Float16* W0XT = (_Float16*)(ws + 2560000);         // 1024*128*2  =   262,144
    _Float16* W0HT = (_Float16*)(ws + 2822144);         // 2 MB
    _Float16* W1XT = (_Float16*)(ws + 4919296);         // 2 MB
    _Float16* W1HT = (_Float16*)(ws + 7016448);         // 2 MB
    _Float16* Hbuf = (_Float16*)(ws + 9113600);         // 4 x 2 MB
    unsigned* bar  = (unsigned*)(ws + 17502208);        // 2 KB barrier region
    _Float16* H0a = Hbuf;
    _Float16* H0b = Hbuf + 1024 * 1024;
    _Float16* H1a = Hbuf + 2 * 1024 * 1024;
    _Float16* H1b = Hbuf + 3 * 1024 * 1024;

    embp_kernel<<<10000, EPAD, 0, stream>>>(emb, EMBP);
    tpad_kernel<<<dim3(4, 32),  dim3(32, 8), 0, stream>>>(W0x, W0XT, EMBD, EPAD, UNITS);
    tpad_kernel<<<dim3(32, 32), dim3(32, 8), 0, stream>>>(W0h, W0HT, UNITS, UNITS, UNITS);
    tpad_kernel<<<dim3(32, 32), dim3(32, 8), 0, stream>>>(W1x, W1XT, UNITS, UNITS, UNITS);
    tpad_kernel<<<dim3(32, 32), dim3(32, 8), 0, stream>>>(W1h, W1HT, UNITS, UNITS, UNITS);
    zero_kernel<<<2048, 256, 0, stream>>>((s8v*)Hbuf);
    hipMemsetAsync(bar, 0, 2048, stream);

    Params P;
    P.x = x; P.EMBP = EMBP; P.W0XT = W0XT; P.W0HT = W0HT; P.W1XT = W1XT; P.W1HT = W1HT;
    P.b0 = b0; P.b1 = b1; P.Wout = Wout; P.bout = bout;
    P.H0a = H0a; P.H0b = H0b; P.H1a = H1a; P.H1b = H1b;
    P.out = out; P.bar = bar;
    void* kargs[] = { &P };
    hipError_t err = hipLaunchCooperativeKernel(
        reinterpret_cast<void*>(rnn_kernel), dim3(NBLK), dim3(256), kargs, 0, stream);

    if (err != hipSuccess) {
        (void)hipGetLastError();   // clear error state; run proven fallback
        GemmTask p;
        p.A0 = EMBP; p.B0T = W0XT; p.xidx = x; p.nch0 = 1; p.lda0 = EPAD; p.ldb0 = EPAD;
        p.A1 = nullptr; p.B1T = nullptr; p.bias = b0; p.out = H0a;
        step_kernel<<<dim3(16, 16, 1), 256, 0, stream>>>(p, p);
        for (int t = 0; t < SEQ; ++t) {
            _Float16* h0cur = (t & 1) ? H0b : H0a;
            GemmTask l1;
            l1.A0 = h0cur; l1.B0T = W1XT; l1.xidx = nullptr;
            l1.nch0 = UNITS / KC; l1.lda0 = UNITS; l1.ldb0 = UNITS;
            l1.A1 = (t == 0) ? nullptr : ((t & 1) ? H1a : H1b);
            l1.B1T = W1HT; l1.bias = b1; l1.out = (t & 1) ? H1b : H1a;
            if (t < SEQ - 1) {
                GemmTask l0;
                l0.A0 = EMBP; l0.B0T = W0XT; l0.xidx = x + (t + 1);
                l0.nch0 = 1; l0.lda0 = EPAD; l0.ldb0 = EPAD;
                l0.A1 = h0cur; l0.B1T = W0HT; l0.bias = b0;
                l0.out = (t & 1) ? H0a : H0b;
                step_kernel<<<dim3(16, 16, 2), 256, 0, stream>>>(l1, l0);
            } else {
                step_kernel<<<dim3(16, 16, 1), 256, 0, stream>>>(l1, l1);
            }
        }
        out_kernel<<<256, 256, 0, stream>>>(H1b, Wout, bout, out);
    }
}

// Round 8
// 2511.136 us; speedup vs baseline: 3.7550x; 1.0062x over previous
//
#include <hip/hip_runtime.h>

// MyRnn persistent v5: double-buffered LDS pipeline.
// R8 change vs R7: one barrier per chunk; prefetch chunk c+1 into the alternate
// LDS buffer right after the barrier, overlapping the IC-latency of H staging
// with chunk c's ds_read+MFMA. Coherence scheme unchanged (H: sc0|sc1
// write-through stores + sc0|sc1 bypass loads; weights: cached).

typedef _Float16 h8v __attribute__((ext_vector_type(8)));
typedef float    f4v __attribute__((ext_vector_type(4)));
typedef short    s8v __attribute__((ext_vector_type(8)));

#define UNITS 1024
#define SEQ   80
#define EMBD  100
#define EPAD  128
#define KC    128
#define NBLK  512
#define BUFH  (64 * KC)   // halves per LDS buffer

__device__ __forceinline__ float tanh_fast(float x) {
    x = fminf(15.f, fmaxf(-15.f, x));   // also scrubs NaN
    float e = __expf(2.f * x);
    return (e - 1.f) / (e + 1.f);
}

template <int AUX>
__device__ __forceinline__ void gl_lds16(const _Float16* g, _Float16* l) {
    __builtin_amdgcn_global_load_lds(
        (const __attribute__((address_space(1))) void*)g,
        (__attribute__((address_space(3))) void*)l, 16, 0, AUX);
}

// coherent (IC-visible) 2-byte store/load for H data
__device__ __forceinline__ void h_store(_Float16* p, float v) {
    _Float16 h = (_Float16)v;
    __hip_atomic_store((short*)p, __builtin_bit_cast(short, h),
                       __ATOMIC_RELAXED, __HIP_MEMORY_SCOPE_AGENT);
}
__device__ __forceinline__ float h_load(const _Float16* p) {
    short s = __hip_atomic_load((const short*)p, __ATOMIC_RELAXED,
                                __HIP_MEMORY_SCOPE_AGENT);
    return (float)__builtin_bit_cast(_Float16, s);
}

// ---------------- prep kernels ----------------

__global__ void embp_kernel(const float* __restrict__ emb, _Float16* __restrict__ embp) {
    int r = blockIdx.x, k = threadIdx.x;
    embp[r * EPAD + k] = (k < EMBD) ? (_Float16)emb[r * EMBD + k] : (_Float16)0.f;
}

__global__ void tpad_kernel(const float* __restrict__ w, _Float16* __restrict__ wt,
                            int K, int Kpad, int N) {
    __shared__ float t[32][33];
    int k0 = blockIdx.x * 32, n0 = blockIdx.y * 32;
    int tx = threadIdx.x, ty = threadIdx.y;
    for (int i = ty; i < 32; i += 8) {
        int k = k0 + i;
        t[i][tx] = (k < K) ? w[(size_t)k * N + n0 + tx] : 0.f;
    }
    __syncthreads();
    for (int i = ty; i < 32; i += 8)
        wt[(size_t)(n0 + i) * Kpad + k0 + tx] = (_Float16)t[tx][i];
}

__global__ void zero_kernel(s8v* __restrict__ p) {
    p[blockIdx.x * 256 + threadIdx.x] = (s8v)0;
}

// ---------------- tile geometry (proven R3/R5/R7) ----------------

struct TileGeom {
    int rq[4], ldsoff[4], koff[4];
    int lane, w, wm, wn, quad, l16;
};

__device__ __forceinline__ TileGeom make_geom(int tid) {
    TileGeom G;
    G.lane = tid & 63; G.w = tid >> 6;
    G.wm = G.w >> 1;   G.wn = G.w & 1;
    G.quad = G.lane >> 4; G.l16 = G.lane & 15;
    #pragma unroll
    for (int q = 0; q < 4; ++q) {
        int g = G.w * 4 + q;
        int r = g * 4 + (G.lane >> 4);
        G.rq[q] = r;
        G.ldsoff[q] = g * 512;
        G.koff[q] = 8 * ((G.lane & 15) ^ (r & 7));
    }
    return G;
}

// single-buffer chunk for the fallback path (unchanged from R7)
template <bool GATHER, int AUXA>
__device__ __forceinline__ void gemm_chunk(
    const TileGeom& G, _Float16* As, _Float16* Bs,
    const _Float16* A, int lda, const int* xi,
    const _Float16* Bt, int ldb, int row0, int col0, int k0, f4v acc[2][2]) {
    #pragma unroll
    for (int q = 0; q < 4; ++q) {
        int r = G.rq[q];
        const _Float16* ap;
        if (GATHER)
            ap = A + (size_t)xi[(size_t)(row0 + r) * SEQ] * EPAD + k0 + G.koff[q];
        else
            ap = A + (size_t)(row0 + r) * lda + k0 + G.koff[q];
        const _Float16* bp = Bt + (size_t)(col0 + r) * ldb + k0 + G.koff[q];
        gl_lds16<AUXA>(ap, As + G.ldsoff[q]);
        gl_lds16<0>(bp, Bs + G.ldsoff[q]);
    }
    __syncthreads();
    #pragma unroll
    for (int kk = 0; kk < 4; ++kk) {
        int us = 8 * ((kk * 4 + G.quad) ^ (G.l16 & 7));
        h8v af[2], bf[2];
        #pragma unroll
        for (int i = 0; i < 2; ++i)
            af[i] = *(const h8v*)(As + (G.wm * 32 + i * 16 + G.l16) * KC + us);
        #pragma unroll
        for (int j = 0; j < 2; ++j)
            bf[j] = *(const h8v*)(Bs + (G.wn * 32 + j * 16 + G.l16) * KC + us);
        #pragma unroll
        for (int i = 0; i < 2; ++i)
            #pragma unroll
            for (int j = 0; j < 2; ++j)
                acc[i][j] = __builtin_amdgcn_mfma_f32_16x16x32_f16(
                    af[i], bf[j], acc[i][j], 0, 0, 0);
    }
    __syncthreads();
}

__device__ __forceinline__ void epilogue(
    const TileGeom& G, f4v acc[2][2], const float* bias, _Float16* outp,
    int row0, int col0) {
    #pragma unroll
    for (int i = 0; i < 2; ++i) {
        int r = row0 + G.wm * 32 + i * 16 + G.quad * 4;
        #pragma unroll
        for (int j = 0; j < 2; ++j) {
            int c = col0 + G.wn * 32 + j * 16 + G.l16;
            float bv = bias[c];
            #pragma unroll
            for (int g2 = 0; g2 < 4; ++g2) {
                float v = tanh_fast(acc[i][j][g2] + bv);
                h_store(outp + (size_t)(r + g2) * UNITS + c, v);
            }
        }
    }
}

// ---------------- persistent cooperative kernel ----------------

struct Params {
    const int* x;
    const _Float16* EMBP; const _Float16* W0XT; const _Float16* W0HT;
    const _Float16* W1XT; const _Float16* W1HT;
    const float* b0; const float* b1; const float* Wout; const float* bout;
    _Float16* H0a; _Float16* H0b; _Float16* H1a; _Float16* H1b;
    float* out;
    unsigned* bar;   // [grp*32] x8 group ctrs, [256] root, [288] generation
};

__device__ __forceinline__ void grid_barrier(unsigned* bar, int bid) {
    __syncthreads();
    if (threadIdx.x == 0) {
        unsigned g = __hip_atomic_load(&bar[288], __ATOMIC_RELAXED, __HIP_MEMORY_SCOPE_AGENT);
        int grp = bid & 7;
        unsigned old = __hip_atomic_fetch_add(&bar[grp * 32], 1u,
                           __ATOMIC_ACQ_REL, __HIP_MEMORY_SCOPE_AGENT);
        bool flipped = false;
        if (old == (NBLK / 8) - 1) {
            __hip_atomic_store(&bar[grp * 32], 0u, __ATOMIC_RELAXED, __HIP_MEMORY_SCOPE_AGENT);
            unsigned o2 = __hip_atomic_fetch_add(&bar[256], 1u,
                              __ATOMIC_ACQ_REL, __HIP_MEMORY_SCOPE_AGENT);
            if (o2 == 7) {
                __hip_atomic_store(&bar[256], 0u, __ATOMIC_RELAXED, __HIP_MEMORY_SCOPE_AGENT);
                __hip_atomic_store(&bar[288], g + 1u, __ATOMIC_RELEASE, __HIP_MEMORY_SCOPE_AGENT);
                flipped = true;
            }
        }
        if (!flipped)
            while (__hip_atomic_load(&bar[288], __ATOMIC_RELAXED, __HIP_MEMORY_SCOPE_AGENT) == g)
                __builtin_amdgcn_s_sleep(1);
    }
    __syncthreads();
}

__launch_bounds__(256, 2)
__global__ void rnn_kernel(Params P) {
    __shared__ _Float16 As[2 * BUFH];   // 2 x 16 KB
    __shared__ _Float16 Bs[2 * BUFH];   // 2 x 16 KB
    TileGeom G = make_geom(threadIdx.x);

    int bid = blockIdx.x;
    int xcd = bid & 7, g = bid >> 3;
    int role = g >> 5, gg = g & 31;                 // role 0: layer1(t), 1: layer0(t+1)
    int j = (xcd << 1) | (gg >> 4), i = gg & 15;    // XCD-local col slice
    int row0 = i * 64, col0 = j * 64;

    for (int phase = 0; phase <= SEQ; ++phase) {
        bool active = role ? (phase < SEQ) : (phase >= 1);
        if (active) {
            const _Float16 *A0, *A1, *B0, *B1; const int* xi;
            const float* bias; _Float16* outp;
            int nch, split;
            if (role) {
                // layer0: h0_p = tanh(emb[x[:,p]] @ W0x + h0_{p-1} @ W0h + b0)
                int p = phase;
                xi = P.x + p;
                A0 = P.EMBP; B0 = P.W0XT;           // chunk 0 (gather, cached)
                A1 = (p & 1) ? P.H0a : P.H0b; B1 = P.W0HT;
                nch = (p > 0) ? 9 : 1; split = 1;
                bias = P.b0; outp = (p & 1) ? P.H0b : P.H0a;
            } else {
                // layer1: h1_p = tanh(h0_p @ W1x + h1_{p-1} @ W1h + b1)
                int p = phase - 1;
                xi = nullptr;
                A0 = (p & 1) ? P.H0b : P.H0a; B0 = P.W1XT;
                A1 = (p & 1) ? P.H1a : P.H1b; B1 = P.W1HT;
                nch = (p > 0) ? 16 : 8; split = 8;
                bias = P.b1; outp = (p & 1) ? P.H1b : P.H1a;
            }

            // stage chunk c into LDS buffer bi (async)
            auto stage = [&](int c, int bi) {
                _Float16* Ad = As + bi * BUFH;
                _Float16* Bd = Bs + bi * BUFH;
                bool s1 = (c >= split);
                const _Float16* Ab = s1 ? A1 : A0;
                const _Float16* Bb = s1 ? B1 : B0;
                int k0 = (s1 ? (c - split) : c) * KC;
                #pragma unroll
                for (int q = 0; q < 4; ++q) {
                    int r = G.rq[q];
                    if (xi && c == 0) {   // gather chunk: EMBP rows, cached
                        const _Float16* ap = Ab +
                            (size_t)xi[(size_t)(row0 + r) * SEQ] * EPAD + G.koff[q];
                        const _Float16* bp = Bb + (size_t)(col0 + r) * EPAD + G.koff[q];
                        gl_lds16<0>(ap, Ad + G.ldsoff[q]);
                        gl_lds16<0>(bp, Bd + G.ldsoff[q]);
                    } else {              // H rows: coherent bypass; weights: cached
                        const _Float16* ap = Ab + (size_t)(row0 + r) * UNITS + k0 + G.koff[q];
                        const _Float16* bp = Bb + (size_t)(col0 + r) * UNITS + k0 + G.koff[q];
                        gl_lds16<17>(ap, Ad + G.ldsoff[q]);
                        gl_lds16<0>(bp, Bd + G.ldsoff[q]);
                    }
                }
            };

            f4v acc[2][2] = {};
            auto compute = [&](int bi) {
                const _Float16* Ab = As + bi * BUFH;
                const _Float16* Bb = Bs + bi * BUFH;
                #pragma unroll
                for (int kk = 0; kk < 4; ++kk) {
                    int us = 8 * ((kk * 4 + G.quad) ^ (G.l16 & 7));
                    h8v af[2], bf[2];
                    #pragma unroll
                    for (int ii = 0; ii < 2; ++ii)
                        af[ii] = *(const h8v*)(Ab + (G.wm * 32 + ii * 16 + G.l16) * KC + us);
                    #pragma unroll
                    for (int jj = 0; jj < 2; ++jj)
                        bf[jj] = *(const h8v*)(Bb + (G.wn * 32 + jj * 16 + G.l16) * KC + us);
                    #pragma unroll
                    for (int ii = 0; ii < 2; ++ii)
                        #pragma unroll
                        for (int jj = 0; jj < 2; ++jj)
                            acc[ii][jj] = __builtin_amdgcn_mfma_f32_16x16x32_f16(
                                af[ii], bf[jj], acc[ii][jj], 0, 0, 0);
                }
            };

            stage(0, 0);
            for (int c = 0; c < nch; ++c) {
                __syncthreads();               // drains stage(c) (vmcnt) + LDS reads of c-1
                if (c + 1 < nch) stage(c + 1, (c + 1) & 1);   // overlaps compute(c)
                compute(c & 1);
            }
            epilogue(G, acc, bias, outp, row0, col0);
        }
        grid_barrier(P.bar, bid);   // includes __syncthreads: protects LDS reuse
    }

    // out[b] = sigmoid(h1_79[b]·Wout + bout); h1_79 in H1b (p=79 odd)
    if (bid < 256) {
        int row = bid * 4 + G.w;
        const _Float16* hr = P.H1b + (size_t)row * UNITS;
        float sacc = 0.f;
        #pragma unroll
        for (int it = 0; it < 16; ++it)
            sacc += h_load(hr + it * 64 + G.lane) * P.Wout[it * 64 + G.lane];
        #pragma unroll
        for (int off = 32; off; off >>= 1) sacc += __shfl_down(sacc, off);
        if (G.lane == 0) P.out[row] = 1.f / (1.f + __expf(-(sacc + P.bout[0])));
    }
}

// ---------------- fallback: proven 81-launch path ----------------

struct GemmTask {
    const _Float16* A0; const _Float16* B0T;
    const int* xidx;
    int nch0, lda0, ldb0;
    const _Float16* A1; const _Float16* B1T;
    const float* bias; _Float16* out;
};

__launch_bounds__(256)
__global__ void step_kernel(GemmTask Ta, GemmTask Tb) {
    GemmTask T = (blockIdx.z == 0) ? Ta : Tb;
    __shared__ _Float16 As[BUFH];
    __shared__ _Float16 Bs[BUFH];
    TileGeom G = make_geom(threadIdx.x);
    int row0 = blockIdx.y * 64, col0 = blockIdx.x * 64;
    f4v acc[2][2] = {};

    if (T.xidx)
        gemm_chunk<true, 0>(G, As, Bs, T.A0, T.lda0, T.xidx, T.B0T, T.ldb0,
                            row0, col0, 0, acc);
    else
        for (int c = 0; c < T.nch0; ++c)
            gemm_chunk<false, 17>(G, As, Bs, T.A0, T.lda0, nullptr, T.B0T, T.ldb0,
                                  row0, col0, c * KC, acc);
    if (T.A1)
        for (int c = 0; c < UNITS / KC; ++c)
            gemm_chunk<false, 17>(G, As, Bs, T.A1, UNITS, nullptr, T.B1T, UNITS,
                                  row0, col0, c * KC, acc);
    epilogue(G, acc, T.bias, T.out, row0, col0);
}

__global__ void out_kernel(const _Float16* __restrict__ h1, const float* __restrict__ wout,
                           const float* __restrict__ bout, float* __restrict__ out) {
    int row  = blockIdx.x * 4 + (threadIdx.x >> 6);
    int lane = threadIdx.x & 63;
    const _Float16* hr = h1 + (size_t)row * UNITS;
    float sacc = 0.f;
    #pragma unroll
    for (int i = 0; i < 16; ++i)
        sacc += h_load(hr + i * 64 + lane) * wout[i * 64 + lane];
    #pragma unroll
    for (int off = 32; off; off >>= 1) sacc += __shfl_down(sacc, off);
    if (lane == 0) out[row] = 1.f / (1.f + __expf(-(sacc + bout[0])));
}

// ---------------- launch ----------------

extern "C" void kernel_launch(void* const* d_in, const int* in_sizes, int n_in,
                              void* d_out, int out_size, void* d_ws, size_t ws_size,
                              hipStream_t stream) {
    const int*   x    = (const int*)d_in[0];
    const float* emb  = (const float*)d_in[1];
    const float* W0x  = (const float*)d_in[2];
    const float* W0h  = (const float*)d_in[3];
    const float* b0   = (const float*)d_in[4];
    const float* W1x  = (const float*)d_in[5];
    const float* W1h  = (const float*)d_in[6];
    const float* b1   = (const float*)d_in[7];
    const float* Wout = (const float*)d_in[8];
    const float* bout = (const float*)d_in[9];
    float* out = (float*)d_out;

    char* ws = (char*)d_ws;
    _Float16* EMBP = (_Float16*)ws;                     // 10000*128*2 = 2,560,000
    _Float16* W0XT = (_Float16*)(ws + 2560000);         // 1024*128*2  =   262,144
    _Float16* W0HT = (_Float16*)(ws + 2822144);         // 2 MB
    _Float16* W1XT = (_Float16*)(ws + 4919296);         // 2 MB
    _Float16* W1HT = (_Float16*)(ws + 7016448);         // 2 MB
    _Float16* Hbuf = (_Float16*)(ws + 9113600);         // 4 x 2 MB
    unsigned* bar  = (unsigned*)(ws + 17502208);        // 2 KB barrier region
    _Float16* H0a = Hbuf;
    _Float16* H0b = Hbuf + 1024 * 1024;
    _Float16* H1a = Hbuf + 2 * 1024 * 1024;
    _Float16* H1b = Hbuf + 3 * 1024 * 1024;

    embp_kernel<<<10000, EPAD, 0, stream>>>(emb, EMBP);
    tpad_kernel<<<dim3(4, 32),  dim3(32, 8), 0, stream>>>(W0x, W0XT, EMBD, EPAD, UNITS);
    tpad_kernel<<<dim3(32, 32), dim3(32, 8), 0, stream>>>(W0h, W0HT, UNITS, UNITS, UNITS);
    tpad_kernel<<<dim3(32, 32), dim3(32, 8), 0, stream>>>(W1x, W1XT, UNITS, UNITS, UNITS);
    tpad_kernel<<<dim3(32, 32), dim3(32, 8), 0, stream>>>(W1h, W1HT, UNITS, UNITS, UNITS);
    zero_kernel<<<2048, 256, 0, stream>>>((s8v*)Hbuf);
    hipMemsetAsync(bar, 0, 2048, stream);

    Params P;
    P.x = x; P.EMBP = EMBP; P.W0XT = W0XT; P.W0HT = W0HT; P.W1XT = W1XT; P.W1HT = W1HT;
    P.b0 = b0; P.b1 = b1; P.Wout = Wout; P.bout = bout;
    P.H0a = H0a; P.H0b = H0b; P.H1a = H1a; P.H1b = H1b;
    P.out = out; P.bar = bar;
    void* kargs[] = { &P };
    hipError_t err = hipLaunchCooperativeKernel(
        reinterpret_cast<void*>(rnn_kernel), dim3(NBLK), dim3(256), kargs, 0, stream);

    if (err != hipSuccess) {
        (void)hipGetLastError();   // clear error state; run proven fallback
        GemmTask p;
        p.A0 = EMBP; p.B0T = W0XT; p.xidx = x; p.nch0 = 1; p.lda0 = EPAD; p.ldb0 = EPAD;
        p.A1 = nullptr; p.B1T = nullptr; p.bias = b0; p.out = H0a;
        step_kernel<<<dim3(16, 16, 1), 256, 0, stream>>>(p, p);
        for (int t = 0; t < SEQ; ++t) {
            _Float16* h0cur = (t & 1) ? H0b : H0a;
            GemmTask l1;
            l1.A0 = h0cur; l1.B0T = W1XT; l1.xidx = nullptr;
            l1.nch0 = UNITS / KC; l1.lda0 = UNITS; l1.ldb0 = UNITS;
            l1.A1 = (t == 0) ? nullptr : ((t & 1) ? H1a : H1b);
            l1.B1T = W1HT; l1.bias = b1; l1.out = (t & 1) ? H1b : H1a;
            if (t < SEQ - 1) {
                GemmTask l0;
                l0.A0 = EMBP; l0.B0T = W0XT; l0.xidx = x + (t + 1);
                l0.nch0 = 1; l0.lda0 = EPAD; l0.ldb0 = EPAD;
                l0.A1 = h0cur; l0.B1T = W0HT; l0.bias = b0;
                l0.out = (t & 1) ? H0a : H0b;
                step_kernel<<<dim3(16, 16, 2), 256, 0, stream>>>(l1, l0);
            } else {
                step_kernel<<<dim3(16, 16, 1), 256, 0, stream>>>(l1, l1);
            }
        }
        out_kernel<<<256, 256, 0, stream>>>(H1b, Wout, bout, out);
    }
}